// Round 2
// baseline (126.849 us; speedup 1.0000x reference)
//
#include <hip/hip_runtime.h>

// Fast HW transcendentals (v_exp_f32 / v_log_f32 / v_rcp_f32), with fallbacks.
#if __has_builtin(__builtin_amdgcn_exp2f)
#define FAST_EXP2(x) __builtin_amdgcn_exp2f(x)
#else
#define FAST_EXP2(x) exp2f(x)
#endif
#if __has_builtin(__builtin_amdgcn_logf)
#define FAST_LOG2(x) __builtin_amdgcn_logf(x)
#else
#define FAST_LOG2(x) log2f(x)
#endif
#if __has_builtin(__builtin_amdgcn_rcpf)
#define FAST_RCP(x) __builtin_amdgcn_rcpf(x)
#else
#define FAST_RCP(x) (1.0f / (x))
#endif

#define LOG2E 1.44269504088896340736f

__device__ __forceinline__ float fast_tanh(float v) {
    // tanh(v) = 1 - 2/(e^{2v}+1);  e^{2v} = 2^{2v*log2e}
    float e = FAST_EXP2(v * (2.0f * LOG2E));
    return fmaf(-2.0f, FAST_RCP(e + 1.0f), 1.0f);
}

__device__ __forceinline__ float fast_sigmoid(float v) {
    return FAST_RCP(1.0f + FAST_EXP2(-v * LOG2E));
}

// 2 rows per thread: weights (scalar loads) amortized over both rows, and the
// two rows' trans-pipe chains (exp/rcp) interleave for 2x ILP on the
// quarter-rate pipe.
__global__ __launch_bounds__(256) void subsurf_kernel(
    const float* __restrict__ x, const float* __restrict__ S1,
    const float* __restrict__ W1, const float* __restrict__ b1,
    const float* __restrict__ W2, const float* __restrict__ b2,
    const float* __restrict__ W3, const float* __restrict__ b3,
    float* __restrict__ out, int n)
{
    int t = blockIdx.x * blockDim.x + threadIdx.x;
    int i0 = 2 * t;
    int i1 = i0 + 1;
    if (i0 >= n) return;
    // Clamp the second row's index so loads stay in-bounds when n is odd;
    // the store below is guarded.
    int i1c = (i1 < n) ? i1 : i0;

    // Coalesced 16B/lane loads; two consecutive rows of x (row = 16B).
    float4 xa = ((const float4*)x)[i0];
    float4 xb = ((const float4*)x)[i1c];
    float xs[2][4] = {{xa.x, xa.y, xa.z, xa.w}, {xb.x, xb.y, xb.z, xb.w}};
    float s1a = S1[i0];
    float s1b = S1[i1c];

    // Bit-match numpy f32 constant arithmetic for lows / (highs - lows).
    const float lows[3]   = {100.0f, 0.01f, 0.01f};
    const float ranges[3] = {500.0f - 100.0f, 100.0f - 0.01f, 10.0f - 0.01f};

    float vals[2][3];
    #pragma unroll
    for (int k = 0; k < 3; ++k) {
        float h1[2][6];
        #pragma unroll
        for (int j = 0; j < 6; ++j) {
            float a0 = b1[k * 6 + j];
            float a1 = a0;
            #pragma unroll
            for (int d = 0; d < 4; ++d) {
                float w = W1[(k * 4 + d) * 6 + j];
                a0 = fmaf(xs[0][d], w, a0);
                a1 = fmaf(xs[1][d], w, a1);
            }
            h1[0][j] = fast_tanh(a0);
            h1[1][j] = fast_tanh(a1);
        }
        float h2[2][6];
        #pragma unroll
        for (int j = 0; j < 6; ++j) {
            float a0 = b2[k * 6 + j];
            float a1 = a0;
            #pragma unroll
            for (int w6 = 0; w6 < 6; ++w6) {
                float w = W2[(k * 6 + w6) * 6 + j];
                a0 = fmaf(h1[0][w6], w, a0);
                a1 = fmaf(h1[1][w6], w, a1);
            }
            h2[0][j] = fast_tanh(a0);
            h2[1][j] = fast_tanh(a1);
        }
        float y0 = b3[k];
        float y1 = y0;
        #pragma unroll
        for (int v = 0; v < 6; ++v) {
            float w = W3[k * 6 + v];
            y0 = fmaf(h2[0][v], w, y0);
            y1 = fmaf(h2[1][v], w, y1);
        }
        vals[0][k] = fmaf(ranges[k], fast_sigmoid(y0), lows[k]);
        vals[1][k] = fmaf(ranges[k], fast_sigmoid(y1), lows[k]);
    }

    float flow[2];
    float s1v[2] = {s1a, s1b};
    #pragma unroll
    for (int r = 0; r < 2; ++r) {
        float S1max = vals[r][0], ks = vals[r][1], nexp = vals[r][2];
        // (S1/S1max)^n in log2 domain: handles S1==0 (log2->-inf, exp2->0).
        float lr = FAST_LOG2(s1v[r]) - FAST_LOG2(S1max);
        float f = ks * FAST_EXP2(nexp * lr);
        flow[r] = fminf(fmaxf(f, 0.0f), S1max);
    }

    if (i1 < n) {
        float2 o;
        o.x = flow[0];
        o.y = flow[1];
        ((float2*)out)[t] = o;
    } else {
        out[i0] = flow[0];
    }
}

extern "C" void kernel_launch(void* const* d_in, const int* in_sizes, int n_in,
                              void* d_out, int out_size, void* d_ws, size_t ws_size,
                              hipStream_t stream) {
    const float* x  = (const float*)d_in[0];
    const float* S1 = (const float*)d_in[1];
    const float* W1 = (const float*)d_in[2];
    const float* b1 = (const float*)d_in[3];
    const float* W2 = (const float*)d_in[4];
    const float* b2 = (const float*)d_in[5];
    const float* W3 = (const float*)d_in[6];
    const float* b3 = (const float*)d_in[7];
    float* out = (float*)d_out;

    int n = out_size;  // N = 2,000,000 rows, one output per row
    int npairs = (n + 1) / 2;
    int block = 256;
    int grid = (npairs + block - 1) / block;
    subsurf_kernel<<<grid, block, 0, stream>>>(x, S1, W1, b1, W2, b2, W3, b3, out, n);
}

// Round 3
// 107.391 us; speedup vs baseline: 1.1812x; 1.1812x over previous
//
#include <hip/hip_runtime.h>

// Fast HW transcendentals (v_exp_f32 / v_log_f32 / v_rcp_f32), with fallbacks.
#if __has_builtin(__builtin_amdgcn_exp2f)
#define FAST_EXP2(x) __builtin_amdgcn_exp2f(x)
#else
#define FAST_EXP2(x) exp2f(x)
#endif
#if __has_builtin(__builtin_amdgcn_logf)
#define FAST_LOG2(x) __builtin_amdgcn_logf(x)
#else
#define FAST_LOG2(x) log2f(x)
#endif
#if __has_builtin(__builtin_amdgcn_rcpf)
#define FAST_RCP(x) __builtin_amdgcn_rcpf(x)
#else
#define FAST_RCP(x) (1.0f / (x))
#endif

#define LOG2E 1.44269504088896340736f

// Packed fp32 pair: arithmetic on this type emits v_pk_fma_f32 / v_pk_mul_f32 /
// v_pk_add_f32 (full-rate packed fp32, gfx90a+) — halves VALU issue count.
typedef float v2f __attribute__((ext_vector_type(2)));

__device__ __forceinline__ v2f v2fma(v2f a, v2f b, v2f c) {
    return __builtin_elementwise_fma(a, b, c);
}

// tanh on a pair. The two elements of a v2f live in separate VGPRs, so the
// scalar trans ops (v_exp_f32 / v_rcp_f32) apply per-element with no
// pack/unpack overhead; the full-rate ops are packed.
__device__ __forceinline__ v2f fast_tanh2(v2f v) {
    v2f t = v * (v2f)(2.0f * LOG2E);   // pk_mul
    v2f e;
    e.x = FAST_EXP2(t.x);
    e.y = FAST_EXP2(t.y);
    v2f d = e + (v2f)(1.0f);           // pk_add
    v2f r;
    r.x = FAST_RCP(d.x);
    r.y = FAST_RCP(d.y);
    return v2fma((v2f)(-2.0f), r, (v2f)(1.0f)); // pk_fma
}

__device__ __forceinline__ float fast_sigmoid(float v) {
    return FAST_RCP(1.0f + FAST_EXP2(-v * LOG2E));
}

// 1 row/thread (occupancy >> weight amortization, per round-2 regression),
// j-dimension packed in fp32 pairs.
__global__ __launch_bounds__(256) void subsurf_kernel(
    const float* __restrict__ x, const float* __restrict__ S1,
    const float* __restrict__ W1, const float* __restrict__ b1,
    const float* __restrict__ W2, const float* __restrict__ b2,
    const float* __restrict__ W3, const float* __restrict__ b3,
    float* __restrict__ out, int n)
{
    int i = blockIdx.x * blockDim.x + threadIdx.x;
    if (i >= n) return;

    // Coalesced 16B/lane load of the 4 features.
    float4 xv = ((const float4*)x)[i];
    float xs[4] = {xv.x, xv.y, xv.z, xv.w};
    float s1 = S1[i];

    // j is the fastest-moving (contiguous) dim of W1/W2/b1/b2, so j-pairs are
    // contiguous 8B-aligned float2s -> uniform s_load_dwordx2.
    const v2f* W1p = (const v2f*)W1;  // [(k*4+d)*3 + jp]
    const v2f* b1p = (const v2f*)b1;  // [k*3 + jp]
    const v2f* W2p = (const v2f*)W2;  // [(k*6+w)*3 + jp]
    const v2f* b2p = (const v2f*)b2;  // [k*3 + jp]

    // Bit-match numpy f32 constant arithmetic for lows / (highs - lows).
    const float lows[3]   = {100.0f, 0.01f, 0.01f};
    const float ranges[3] = {500.0f - 100.0f, 100.0f - 0.01f, 10.0f - 0.01f};

    float vals[3];
    #pragma unroll
    for (int k = 0; k < 3; ++k) {
        float h1[6];
        #pragma unroll
        for (int jp = 0; jp < 3; ++jp) {
            v2f acc = b1p[k * 3 + jp];
            #pragma unroll
            for (int d = 0; d < 4; ++d)
                acc = v2fma((v2f)(xs[d]), W1p[(k * 4 + d) * 3 + jp], acc);
            v2f th = fast_tanh2(acc);
            h1[2 * jp]     = th.x;
            h1[2 * jp + 1] = th.y;
        }
        float h2[6];
        #pragma unroll
        for (int jp = 0; jp < 3; ++jp) {
            v2f acc = b2p[k * 3 + jp];
            #pragma unroll
            for (int w = 0; w < 6; ++w)
                acc = v2fma((v2f)(h1[w]), W2p[(k * 6 + w) * 3 + jp], acc);
            v2f th = fast_tanh2(acc);
            h2[2 * jp]     = th.x;
            h2[2 * jp + 1] = th.y;
        }
        // Layer 3: keep scalar sequential order (bit-matches prior rounds).
        float y = b3[k];
        #pragma unroll
        for (int v = 0; v < 6; ++v)
            y = fmaf(h2[v], W3[k * 6 + v], y);
        vals[k] = fmaf(ranges[k], fast_sigmoid(y), lows[k]);
    }

    float S1max = vals[0], ks = vals[1], nexp = vals[2];
    // (S1/S1max)^n in log2 domain: handles S1==0 (log2->-inf, exp2->0).
    float lr = FAST_LOG2(s1) - FAST_LOG2(S1max);
    float flow = ks * FAST_EXP2(nexp * lr);
    flow = fminf(fmaxf(flow, 0.0f), S1max);
    out[i] = flow;
}

extern "C" void kernel_launch(void* const* d_in, const int* in_sizes, int n_in,
                              void* d_out, int out_size, void* d_ws, size_t ws_size,
                              hipStream_t stream) {
    const float* x  = (const float*)d_in[0];
    const float* S1 = (const float*)d_in[1];
    const float* W1 = (const float*)d_in[2];
    const float* b1 = (const float*)d_in[3];
    const float* W2 = (const float*)d_in[4];
    const float* b2 = (const float*)d_in[5];
    const float* W3 = (const float*)d_in[6];
    const float* b3 = (const float*)d_in[7];
    float* out = (float*)d_out;

    int n = out_size;  // N = 2,000,000 rows, one output per row
    int block = 256;
    int grid = (n + block - 1) / block;
    subsurf_kernel<<<grid, block, 0, stream>>>(x, S1, W1, b1, W2, b2, W3, b3, out, n);
}

// Round 7
// 106.606 us; speedup vs baseline: 1.1899x; 1.0074x over previous
//
#include <hip/hip_runtime.h>

// Fast HW transcendentals (v_exp_f32 / v_log_f32 / v_rcp_f32), with fallbacks.
#if __has_builtin(__builtin_amdgcn_exp2f)
#define FAST_EXP2(x) __builtin_amdgcn_exp2f(x)
#else
#define FAST_EXP2(x) exp2f(x)
#endif
#if __has_builtin(__builtin_amdgcn_logf)
#define FAST_LOG2(x) __builtin_amdgcn_logf(x)
#else
#define FAST_LOG2(x) log2f(x)
#endif
#if __has_builtin(__builtin_amdgcn_rcpf)
#define FAST_RCP(x) __builtin_amdgcn_rcpf(x)
#else
#define FAST_RCP(x) (1.0f / (x))
#endif

#define LOG2E 1.44269504088896340736f

// Compiler-generated vector math ONLY. The <2 x float> IR ops are elementwise
// by construction — correctness does not depend on VOP3P op_sel conventions
// (rounds 4-6 condemned the inline-asm v_pk_* path: modifier semantics on
// packed-fp32 did not match the ISA-text reading).
typedef float v2f __attribute__((ext_vector_type(2)));

__device__ __forceinline__ v2f v2fma(v2f a, v2f b, v2f c) {
    return __builtin_elementwise_fma(a, b, c);
}

// tanh on a pair; per-element math/order identical to rounds 1-3.
__device__ __forceinline__ v2f fast_tanh2(v2f v) {
    v2f t = v * (v2f)(2.0f * LOG2E);
    v2f e;
    e.x = FAST_EXP2(t.x);
    e.y = FAST_EXP2(t.y);
    v2f d = e + (v2f)(1.0f);
    v2f r;
    r.x = FAST_RCP(d.x);
    r.y = FAST_RCP(d.y);
    return v2fma((v2f)(-2.0f), r, (v2f)(1.0f));
}

__device__ __forceinline__ float fast_sigmoid(float v) {
    return FAST_RCP(1.0f + FAST_EXP2(-v * LOG2E));
}

// R3 structure + ONE change: weights staged to LDS once per block.
// Wave-uniform ds_read with immediate offsets -> free broadcast on the LDS
// pipe, replacing ~70 per-wave s_loads + lgkmcnt stalls in the unrolled body.
__global__ __launch_bounds__(256) void subsurf_kernel(
    const float* __restrict__ x, const float* __restrict__ S1,
    const float* __restrict__ W1, const float* __restrict__ b1,
    const float* __restrict__ W2, const float* __restrict__ b2,
    const float* __restrict__ W3, const float* __restrict__ b3,
    float* __restrict__ out, int n)
{
    // Layout: W1[0..72) b1[72..90) W2[90..198) b2[198..216) W3[216..234) b3[234..237)
    __shared__ __align__(16) float w[240];
    int t = threadIdx.x;
    if (t < 72)       w[t] = W1[t];
    else if (t < 90)  w[t] = b1[t - 72];
    else if (t < 198) w[t] = W2[t - 90];
    else if (t < 216) w[t] = b2[t - 198];
    else if (t < 234) w[t] = W3[t - 216];
    else if (t < 237) w[t] = b3[t - 234];
    __syncthreads();

    int i = blockIdx.x * blockDim.x + t;
    if (i >= n) return;

    const v2f* W1p = (const v2f*)(w + 0);    // [(k*4+d)*3 + jp]
    const v2f* b1p = (const v2f*)(w + 72);   // [k*3 + jp]
    const v2f* W2p = (const v2f*)(w + 90);   // [(k*6+ww)*3 + jp]
    const v2f* b2p = (const v2f*)(w + 198);  // [k*3 + jp]
    const float* W3s = w + 216;              // [k*6 + v]
    const float* b3s = w + 234;              // [k]

    // Coalesced 16B/lane load of the 4 features.
    float4 xv = ((const float4*)x)[i];
    float xs[4] = {xv.x, xv.y, xv.z, xv.w};
    float s1 = S1[i];

    // Bit-match numpy f32 constant arithmetic for lows / (highs - lows).
    const float lows[3]   = {100.0f, 0.01f, 0.01f};
    const float ranges[3] = {500.0f - 100.0f, 100.0f - 0.01f, 10.0f - 0.01f};

    float vals[3];
    #pragma unroll
    for (int k = 0; k < 3; ++k) {
        float h1[6];
        #pragma unroll
        for (int jp = 0; jp < 3; ++jp) {
            v2f acc = b1p[k * 3 + jp];
            #pragma unroll
            for (int d = 0; d < 4; ++d)
                acc = v2fma((v2f)(xs[d]), W1p[(k * 4 + d) * 3 + jp], acc);
            v2f th = fast_tanh2(acc);
            h1[2 * jp]     = th.x;
            h1[2 * jp + 1] = th.y;
        }
        float h2[6];
        #pragma unroll
        for (int jp = 0; jp < 3; ++jp) {
            v2f acc = b2p[k * 3 + jp];
            #pragma unroll
            for (int ww = 0; ww < 6; ++ww)
                acc = v2fma((v2f)(h1[ww]), W2p[(k * 6 + ww) * 3 + jp], acc);
            v2f th = fast_tanh2(acc);
            h2[2 * jp]     = th.x;
            h2[2 * jp + 1] = th.y;
        }
        // Layer 3: scalar sequential order (bit-matches prior rounds).
        float y = b3s[k];
        #pragma unroll
        for (int v = 0; v < 6; ++v)
            y = fmaf(h2[v], W3s[k * 6 + v], y);
        vals[k] = fmaf(ranges[k], fast_sigmoid(y), lows[k]);
    }

    float S1max = vals[0], ks = vals[1], nexp = vals[2];
    // (S1/S1max)^n in log2 domain: handles S1==0 (log2->-inf, exp2->0).
    float lr = FAST_LOG2(s1) - FAST_LOG2(S1max);
    float flow = ks * FAST_EXP2(nexp * lr);
    flow = fminf(fmaxf(flow, 0.0f), S1max);
    out[i] = flow;
}

extern "C" void kernel_launch(void* const* d_in, const int* in_sizes, int n_in,
                              void* d_out, int out_size, void* d_ws, size_t ws_size,
                              hipStream_t stream) {
    const float* x  = (const float*)d_in[0];
    const float* S1 = (const float*)d_in[1];
    const float* W1 = (const float*)d_in[2];
    const float* b1 = (const float*)d_in[3];
    const float* W2 = (const float*)d_in[4];
    const float* b2 = (const float*)d_in[5];
    const float* W3 = (const float*)d_in[6];
    const float* b3 = (const float*)d_in[7];
    float* out = (float*)d_out;

    int n = out_size;  // N = 2,000,000 rows, one output per row
    int block = 256;
    int grid = (n + block - 1) / block;
    subsurf_kernel<<<grid, block, 0, stream>>>(x, S1, W1, b1, W2, b2, W3, b3, out, n);
}